// Round 20
// baseline (26.128 us; speedup 1.0000x reference)
//
#include <hip/hip_runtime.h>
#include <hip/hip_bf16.h>

// CrossSigmoidFocalLoss: mean over (N,C) of focal_w * bce * row_w * cross_mask
// Per element (p = sigmoid(x)):
//   c==t: 0.25 * sigmoid(-x)^2 * softplus(-x)
//   c!=t: 0.75 * sigmoid(x)^2  * softplus(x)   [* schema bit if t==C]
// One exp/rcp/log per element; softplus(-x) = softplus(x) - x.
// weight < 2^16 so schema bits for c>=16 are 0 (c0>=32 shift guarded).
//
// Ledger: R8 __threadfence/block=+66us. R9 same-addr arrival atomics(+nt)=+14.6us.
// R11 staging neutral. R12 occupancy(4096blk) neutral. R14 VALU-cut neutral.
// R17 probe: main ~17-18us even L3-warm (4.8 TB/s eff = 78% of achievable).
// R18 one-epoch reduce: -0.8 -> reduce path is node gap/drain (~6us), fusion
// poisoned. R19 one-batch geometry: -0.7.
// THIS ROUND (single variable): nontemporal load on pred ONLY (isolated from
// R9's finalizer confound). pred is stream-once -> skip L2/L3 allocation tax.
// targets/weight keep normal caching (20x reuse).

#define NCLS 80
#define C4   (NCLS / 4)              // 20 float4 per row
#define NBLOCKS 2048
#define NTHREADS 256
#define KIT 10
#define STRIDE (NBLOCKS * NTHREADS)  // 524,288 threads = 8192 waves = 1 batch

typedef float f32x4 __attribute__((ext_vector_type(4)));

__device__ __forceinline__ float quad_term(f32x4 x4, int t, float w, int c0) {
    const int   wi  = (int)w;
    const bool  neg = (t == NCLS);
    const float qn  = (w > 0.0f) ? 0.75f : 0.0f;
    const float qp  = (w > 0.0f) ? 0.25f : 0.0f;
    const int   wsh   = (c0 < 32) ? (wi >> c0) : 0;   // guard shift >= 32 (UB)
    const int   maskA = neg ? (wsh & 15) : 15;        // neg rows: schema bits; pos: all
    float acc = 0.0f;
    #pragma unroll
    for (int j = 0; j < 4; ++j) {
        const float x   = x4[j];
        const float e   = __expf(-fabsf(x));            // v_exp path
        const float d   = 1.0f + e;
        const float r   = __builtin_amdgcn_rcpf(d);     // v_rcp
        const float sB  = e * r;
        const bool  f   = (x >= 0.0f);
        const float s   = f ? r : sB;                   // sigmoid(x)
        const float s1  = f ? sB : r;                   // sigmoid(-x)
        const float lg  = __log2f(d);                   // v_log
        const float sp  = __builtin_fmaf(lg, 0.69314718055994531f, fmaxf(x, 0.0f));
        const float sp1 = sp - x;                       // softplus(-x)
        const float g   = (s * s) * sp;
        const float g1  = (s1 * s1) * sp1;
        const float cN  = ((maskA >> j) & 1) ? qn : 0.0f;
        const bool  ist = ((c0 + j) == t);              // never true on neg rows
        acc += ist ? (qp * g1) : (cN * g);
    }
    return acc;
}

template<int KITERS>
__global__ void __launch_bounds__(NTHREADS, 8)
cfs_main(const float* __restrict__ pred,
         const int*   __restrict__ targets,
         const float* __restrict__ weight,
         float* __restrict__ partials,
         int total4) {
    const int tid = blockIdx.x * NTHREADS + threadIdx.x;

    float acc = 0.0f;
    if constexpr (KITERS > 0) {
        #pragma unroll
        for (int k = 0; k < KITERS; ++k) {
            const int i  = tid + k * STRIDE;
            const int n  = i / C4;              // magic-mul divide by 20
            const int c0 = (i - n * C4) * 4;
            // pred is stream-once: nt load skips cache allocation
            const f32x4 x4 = __builtin_nontemporal_load(
                reinterpret_cast<const f32x4*>(pred) + i);
            acc += quad_term(x4, targets[n], weight[n], c0);
        }
    } else {
        for (int i = tid; i < total4; i += STRIDE) {
            const int n  = i / C4;
            const int c0 = (i - n * C4) * 4;
            const f32x4 x4 = __builtin_nontemporal_load(
                reinterpret_cast<const f32x4*>(pred) + i);
            acc += quad_term(x4, targets[n], weight[n], c0);
        }
    }

    // wave (64-lane) reduction
    #pragma unroll
    for (int off = 32; off > 0; off >>= 1)
        acc += __shfl_down(acc, off, 64);

    __shared__ float smem[NTHREADS / 64];
    const int lane = threadIdx.x & 63;
    const int wid  = threadIdx.x >> 6;
    if (lane == 0) smem[wid] = acc;
    __syncthreads();
    if (threadIdx.x == 0)
        partials[blockIdx.x] = smem[0] + smem[1] + smem[2] + smem[3];
}

// Specialized reduce for NBLOCKS==2048 (= 512 f32x4): both loads per thread
// issue before any use -> one latency epoch. Fixed-order -> deterministic.
__global__ void __launch_bounds__(NTHREADS)
cfs_reduce2048(const float* __restrict__ partials, float* __restrict__ out,
               float scale) {
    const int t = threadIdx.x;
    const f32x4* p4 = reinterpret_cast<const f32x4*>(partials);
    const f32x4 a = p4[t];
    const f32x4 b = p4[t + 256];
    float acc = ((a[0] + a[1]) + (a[2] + a[3]))
              + ((b[0] + b[1]) + (b[2] + b[3]));

    #pragma unroll
    for (int off = 32; off > 0; off >>= 1)
        acc += __shfl_down(acc, off, 64);

    __shared__ float smem[NTHREADS / 64];
    const int lane = t & 63;
    const int wid  = t >> 6;
    if (lane == 0) smem[wid] = acc;
    __syncthreads();
    if (t == 0)
        out[0] = (smem[0] + smem[1] + smem[2] + smem[3]) * scale;
}

__global__ void __launch_bounds__(NTHREADS)
cfs_reduce_gen(const float* __restrict__ partials, float* __restrict__ out,
               int nparts, float scale) {
    float acc = 0.0f;
    for (int i = threadIdx.x; i < nparts; i += NTHREADS)
        acc += partials[i];
    #pragma unroll
    for (int off = 32; off > 0; off >>= 1)
        acc += __shfl_down(acc, off, 64);

    __shared__ float smem[NTHREADS / 64];
    const int lane = threadIdx.x & 63;
    const int wid  = threadIdx.x >> 6;
    if (lane == 0) smem[wid] = acc;
    __syncthreads();
    if (threadIdx.x == 0)
        out[0] = (smem[0] + smem[1] + smem[2] + smem[3]) * scale;
}

extern "C" void kernel_launch(void* const* d_in, const int* in_sizes, int n_in,
                              void* d_out, int out_size, void* d_ws, size_t ws_size,
                              hipStream_t stream) {
    const float* pred     = (const float*)d_in[0];
    const int*   targets  = (const int*)  d_in[1];
    const float* weight   = (const float*)d_in[2];
    float*       out      = (float*)d_out;
    float*       partials = (float*)d_ws;   // NBLOCKS floats of scratch

    const int n_rows = in_sizes[1];          // 262144
    const int total4 = n_rows * C4;          // 5,242,880
    const float inv_total = 1.0f / (float)(n_rows * NCLS);

    if (total4 == KIT * STRIDE) {
        cfs_main<KIT><<<NBLOCKS, NTHREADS, 0, stream>>>(pred, targets, weight, partials, total4);
        cfs_reduce2048<<<1, NTHREADS, 0, stream>>>(partials, out, inv_total);
    } else {
        cfs_main<0><<<NBLOCKS, NTHREADS, 0, stream>>>(pred, targets, weight, partials, total4);
        cfs_reduce_gen<<<1, NTHREADS, 0, stream>>>(partials, out, NBLOCKS, inv_total);
    }
}

// Round 21
// 25.076 us; speedup vs baseline: 1.0420x; 1.0420x over previous
//
#include <hip/hip_runtime.h>
#include <hip/hip_bf16.h>

// CrossSigmoidFocalLoss: mean over (N,C) of focal_w * bce * row_w * cross_mask
// Per element (p = sigmoid(x)):
//   c==t: 0.25 * sigmoid(-x)^2 * softplus(-x)
//   c!=t: 0.75 * sigmoid(x)^2  * softplus(x)   [* schema bit if t==C]
// One exp/rcp/log per element; softplus(-x) = softplus(x) - x.
// weight < 2^16 so schema bits for c>=16 are 0 (c0>=32 shift guarded).
//
// FINAL LEDGER (20 rounds):
//   R1->R5: div-seq removal, branchless, poly softplus, unroll: 50.2 -> 27.5us.
//   R8: per-block __threadfence = 2048 L2 writebacks = +66us (catastrophic).
//   R9: same-addr arrival atomics = +10-30us tail (catastrophic).
//   R11 staging, R12 occupancy-raise, R14 VALU-cut (~30%): all neutral.
//   R17 probe: main ~17us even L3-warm -> internal stream floor, not HBM-cold.
//   R18 one-epoch reduce: -0.8us (reduce path is node gap, not load latency).
//   R19 one-batch geometry (2048blk x KIT=10 x 8 waves/SIMD): -0.7us. BEST=24.90.
//   R20 nontemporal pred loads: +1.2us (nt defeats L2 read-combining) -> reverted.
// Structure: two kernels; device fusion blocked (fences/atomics poison per R8/R9,
// no state-free last-arrival under no-re-poison replays, memset is a node too).

#define NCLS 80
#define C4   (NCLS / 4)              // 20 float4 per row
#define NBLOCKS 2048
#define NTHREADS 256
#define KIT 10
#define STRIDE (NBLOCKS * NTHREADS)  // 524,288 threads = 8192 waves = 1 batch

typedef float f32x4 __attribute__((ext_vector_type(4)));

__device__ __forceinline__ float quad_term(f32x4 x4, int t, float w, int c0) {
    const int   wi  = (int)w;
    const bool  neg = (t == NCLS);
    const float qn  = (w > 0.0f) ? 0.75f : 0.0f;
    const float qp  = (w > 0.0f) ? 0.25f : 0.0f;
    const int   wsh   = (c0 < 32) ? (wi >> c0) : 0;   // guard shift >= 32 (UB)
    const int   maskA = neg ? (wsh & 15) : 15;        // neg rows: schema bits; pos: all
    float acc = 0.0f;
    #pragma unroll
    for (int j = 0; j < 4; ++j) {
        const float x   = x4[j];
        const float e   = __expf(-fabsf(x));            // v_exp path
        const float d   = 1.0f + e;
        const float r   = __builtin_amdgcn_rcpf(d);     // v_rcp
        const float sB  = e * r;
        const bool  f   = (x >= 0.0f);
        const float s   = f ? r : sB;                   // sigmoid(x)
        const float s1  = f ? sB : r;                   // sigmoid(-x)
        const float lg  = __log2f(d);                   // v_log
        const float sp  = __builtin_fmaf(lg, 0.69314718055994531f, fmaxf(x, 0.0f));
        const float sp1 = sp - x;                       // softplus(-x)
        const float g   = (s * s) * sp;
        const float g1  = (s1 * s1) * sp1;
        const float cN  = ((maskA >> j) & 1) ? qn : 0.0f;
        const bool  ist = ((c0 + j) == t);              // never true on neg rows
        acc += ist ? (qp * g1) : (cN * g);
    }
    return acc;
}

template<int KITERS>
__global__ void __launch_bounds__(NTHREADS, 8)
cfs_main(const float* __restrict__ pred,
         const int*   __restrict__ targets,
         const float* __restrict__ weight,
         float* __restrict__ partials,
         int total4) {
    const int tid = blockIdx.x * NTHREADS + threadIdx.x;

    float acc = 0.0f;
    if constexpr (KITERS > 0) {
        #pragma unroll
        for (int k = 0; k < KITERS; ++k) {
            const int i  = tid + k * STRIDE;
            const int n  = i / C4;              // magic-mul divide by 20
            const int c0 = (i - n * C4) * 4;
            const f32x4 x4 = reinterpret_cast<const f32x4*>(pred)[i];
            acc += quad_term(x4, targets[n], weight[n], c0);
        }
    } else {
        for (int i = tid; i < total4; i += STRIDE) {
            const int n  = i / C4;
            const int c0 = (i - n * C4) * 4;
            const f32x4 x4 = reinterpret_cast<const f32x4*>(pred)[i];
            acc += quad_term(x4, targets[n], weight[n], c0);
        }
    }

    // wave (64-lane) reduction
    #pragma unroll
    for (int off = 32; off > 0; off >>= 1)
        acc += __shfl_down(acc, off, 64);

    __shared__ float smem[NTHREADS / 64];
    const int lane = threadIdx.x & 63;
    const int wid  = threadIdx.x >> 6;
    if (lane == 0) smem[wid] = acc;
    __syncthreads();
    if (threadIdx.x == 0)
        partials[blockIdx.x] = smem[0] + smem[1] + smem[2] + smem[3];
}

// Specialized reduce for NBLOCKS==2048 (= 512 f32x4): both loads per thread
// issue before any use -> one latency epoch. Fixed-order -> deterministic.
__global__ void __launch_bounds__(NTHREADS)
cfs_reduce2048(const float* __restrict__ partials, float* __restrict__ out,
               float scale) {
    const int t = threadIdx.x;
    const f32x4* p4 = reinterpret_cast<const f32x4*>(partials);
    const f32x4 a = p4[t];
    const f32x4 b = p4[t + 256];
    float acc = ((a[0] + a[1]) + (a[2] + a[3]))
              + ((b[0] + b[1]) + (b[2] + b[3]));

    #pragma unroll
    for (int off = 32; off > 0; off >>= 1)
        acc += __shfl_down(acc, off, 64);

    __shared__ float smem[NTHREADS / 64];
    const int lane = t & 63;
    const int wid  = t >> 6;
    if (lane == 0) smem[wid] = acc;
    __syncthreads();
    if (t == 0)
        out[0] = (smem[0] + smem[1] + smem[2] + smem[3]) * scale;
}

__global__ void __launch_bounds__(NTHREADS)
cfs_reduce_gen(const float* __restrict__ partials, float* __restrict__ out,
               int nparts, float scale) {
    float acc = 0.0f;
    for (int i = threadIdx.x; i < nparts; i += NTHREADS)
        acc += partials[i];
    #pragma unroll
    for (int off = 32; off > 0; off >>= 1)
        acc += __shfl_down(acc, off, 64);

    __shared__ float smem[NTHREADS / 64];
    const int lane = threadIdx.x & 63;
    const int wid  = threadIdx.x >> 6;
    if (lane == 0) smem[wid] = acc;
    __syncthreads();
    if (threadIdx.x == 0)
        out[0] = (smem[0] + smem[1] + smem[2] + smem[3]) * scale;
}

extern "C" void kernel_launch(void* const* d_in, const int* in_sizes, int n_in,
                              void* d_out, int out_size, void* d_ws, size_t ws_size,
                              hipStream_t stream) {
    const float* pred     = (const float*)d_in[0];
    const int*   targets  = (const int*)  d_in[1];
    const float* weight   = (const float*)d_in[2];
    float*       out      = (float*)d_out;
    float*       partials = (float*)d_ws;   // NBLOCKS floats of scratch

    const int n_rows = in_sizes[1];          // 262144
    const int total4 = n_rows * C4;          // 5,242,880
    const float inv_total = 1.0f / (float)(n_rows * NCLS);

    if (total4 == KIT * STRIDE) {
        cfs_main<KIT><<<NBLOCKS, NTHREADS, 0, stream>>>(pred, targets, weight, partials, total4);
        cfs_reduce2048<<<1, NTHREADS, 0, stream>>>(partials, out, inv_total);
    } else {
        cfs_main<0><<<NBLOCKS, NTHREADS, 0, stream>>>(pred, targets, weight, partials, total4);
        cfs_reduce_gen<<<1, NTHREADS, 0, stream>>>(partials, out, NBLOCKS, inv_total);
    }
}